// Round 1
// baseline (1423.143 us; speedup 1.0000x reference)
//
#include <hip/hip_runtime.h>

using short8 = __attribute__((ext_vector_type(8))) short;
using f32x4  = __attribute__((ext_vector_type(4))) float;
typedef unsigned short ushort_t;

__device__ __forceinline__ unsigned short f2bf(float f) {
  unsigned u = __float_as_uint(f);
  u += 0x7FFF + ((u >> 16) & 1);   // round-to-nearest-even
  return (unsigned short)(u >> 16);
}

__device__ __forceinline__ int swz(int r, int byteoff) {
  return byteoff ^ ((r & 7) << 4);   // G4 XOR swizzle: kills 16-way conflict on 128B-stride rows
}

// ---------------- router: logits -> softmax -> top2 -> dense combine w[T,8] ----------------
__global__ void router_kernel(const float* __restrict__ x, const float* __restrict__ gW,
                              float* __restrict__ w) {
  int t = blockIdx.x;
  int lane = threadIdx.x;  // 64 threads = 1 wave
  float acc[8] = {0.f,0.f,0.f,0.f,0.f,0.f,0.f,0.f};
  const float* xt = x + (size_t)t * 2048;
  for (int i = lane; i < 2048; i += 64) {
    float xv = xt[i];
#pragma unroll
    for (int e = 0; e < 8; e++) acc[e] += xv * gW[e * 2048 + i];
  }
#pragma unroll
  for (int e = 0; e < 8; e++) {
#pragma unroll
    for (int off = 32; off > 0; off >>= 1) acc[e] += __shfl_xor(acc[e], off);
  }
  if (lane == 0) {
    float mx = acc[0];
    for (int e = 1; e < 8; e++) mx = fmaxf(mx, acc[e]);
    float p[8], se = 0.f;
    for (int e = 0; e < 8; e++) { p[e] = __expf(acc[e] - mx); se += p[e]; }
    for (int e = 0; e < 8; e++) p[e] /= se;
    int i1 = 0;
    for (int e = 1; e < 8; e++) if (p[e] > p[i1]) i1 = e;
    int i2 = (i1 == 0) ? 1 : 0;
    for (int e = 0; e < 8; e++) if (e != i1 && p[e] > p[i2]) i2 = e;
    for (int e = 0; e < 8; e++) w[t * 8 + e] = (e == i1 || e == i2) ? p[e] : 0.f;
  }
}

// ---------------- x f32 -> bf16 ----------------
__global__ void cvt_kernel(const float* __restrict__ x, ushort_t* __restrict__ xb, int n) {
  int i = (blockIdx.x * blockDim.x + threadIdx.x) * 4;
  if (i >= n) return;
  float4 v = *(const float4*)(x + i);
  ushort4 o = { f2bf(v.x), f2bf(v.y), f2bf(v.z), f2bf(v.w) };
  *(ushort4*)(xb + i) = o;
}

// ---------------- fused gate+up GEMM: H = bf16( silu(A@Bg^T) * (A@Bu^T) ) ----------------
// A: [2048,K] bf16 row-major; Bg,Bu: [N,K] f32 row-major; H: [2048,N] bf16
#define BM 128
#define BN 128
#define BKW 64

__global__ __launch_bounds__(256, 2) void gateup_kernel(
    const ushort_t* __restrict__ A, const float* __restrict__ Bg,
    const float* __restrict__ Bu, ushort_t* __restrict__ H, int N, int K) {
  __shared__ char smem[3 * BM * BKW * 2];   // As | Bgs | Bus, 16KB each
  const int AOFF = 0, GOFF = BM * BKW * 2, UOFF = 2 * BM * BKW * 2;
  int m0 = blockIdx.x * BM, n0 = blockIdx.y * BN;
  int tid = threadIdx.x;
  int c = tid & 7, rbase = tid >> 3;
  int wid = tid >> 6, lane = tid & 63;
  int wr = wid >> 1, wc = wid & 1;
  int lr = lane & 15, lk = lane >> 4;

  f32x4 accg[4][4] = {};
  f32x4 accu[4][4] = {};

  for (int k0 = 0; k0 < K; k0 += BKW) {
    {  // stage A (bf16, raw copy)
      const ushort_t* Ap = A + (size_t)m0 * K + k0;
#pragma unroll
      for (int i = 0; i < 4; i++) {
        int rr = rbase + 32 * i;
        short8 v = *(const short8*)(Ap + (size_t)rr * K + c * 8);
        *(short8*)(smem + AOFF + swz(rr, rr * 128 + c * 16)) = v;
      }
    }
#pragma unroll
    for (int which = 0; which < 2; which++) {  // stage Bg/Bu with f32->bf16
      const float* Bp = (which ? Bu : Bg) + (size_t)n0 * K + k0;
      int off = which ? UOFF : GOFF;
#pragma unroll
      for (int i = 0; i < 4; i++) {
        int rr = rbase + 32 * i;
        const float* p = Bp + (size_t)rr * K + c * 8;
        float4 v0 = *(const float4*)p;
        float4 v1 = *(const float4*)(p + 4);
        short8 o;
        o[0] = (short)f2bf(v0.x); o[1] = (short)f2bf(v0.y);
        o[2] = (short)f2bf(v0.z); o[3] = (short)f2bf(v0.w);
        o[4] = (short)f2bf(v1.x); o[5] = (short)f2bf(v1.y);
        o[6] = (short)f2bf(v1.z); o[7] = (short)f2bf(v1.w);
        *(short8*)(smem + off + swz(rr, rr * 128 + c * 16)) = o;
      }
    }
    __syncthreads();
#pragma unroll
    for (int ks = 0; ks < 2; ks++) {
      short8 af[4], bg[4], bu[4];
#pragma unroll
      for (int m = 0; m < 4; m++) {
        int rr = wr * 64 + m * 16 + lr;
        af[m] = *(const short8*)(smem + AOFF + swz(rr, rr * 128 + ks * 64 + lk * 16));
      }
#pragma unroll
      for (int n = 0; n < 4; n++) {
        int cc = wc * 64 + n * 16 + lr;
        bg[n] = *(const short8*)(smem + GOFF + swz(cc, cc * 128 + ks * 64 + lk * 16));
        bu[n] = *(const short8*)(smem + UOFF + swz(cc, cc * 128 + ks * 64 + lk * 16));
      }
#pragma unroll
      for (int m = 0; m < 4; m++) {
#pragma unroll
        for (int n = 0; n < 4; n++) {
          accg[m][n] = __builtin_amdgcn_mfma_f32_16x16x32_bf16(af[m], bg[n], accg[m][n], 0, 0, 0);
          accu[m][n] = __builtin_amdgcn_mfma_f32_16x16x32_bf16(af[m], bu[n], accu[m][n], 0, 0, 0);
        }
      }
    }
    __syncthreads();
  }
  // epilogue: h = silu(g)*u -> bf16   (C/D layout: col=lane&15, row=(lane>>4)*4+j)
#pragma unroll
  for (int m = 0; m < 4; m++) {
    int row = m0 + wr * 64 + m * 16 + lk * 4;
#pragma unroll
    for (int n = 0; n < 4; n++) {
      int col = n0 + wc * 64 + n * 16 + lr;
#pragma unroll
      for (int j = 0; j < 4; j++) {
        float g = accg[m][n][j], u = accu[m][n][j];
        float s = g / (1.f + __expf(-g));
        H[(size_t)(row + j) * N + col] = f2bf(s * u);
      }
    }
  }
}

// ---------------- down GEMM: C[2048,N] (=|+=) scale[t] * (A @ B^T) ----------------
// A: [2048,K] bf16; B: [N,K] f32; C: [2048,N] f32; scale: per-row f32 stride 8, or null (store)
__global__ __launch_bounds__(256, 2) void down_kernel(
    const ushort_t* __restrict__ A, const float* __restrict__ B,
    float* __restrict__ C, const float* __restrict__ scale, int N, int K) {
  __shared__ char smem[2 * BM * BKW * 2];   // As | Bs
  const int AOFF = 0, BOFF = BM * BKW * 2;
  int m0 = blockIdx.x * BM, n0 = blockIdx.y * BN;
  int tid = threadIdx.x;
  int c = tid & 7, rbase = tid >> 3;
  int wid = tid >> 6, lane = tid & 63;
  int wr = wid >> 1, wc = wid & 1;
  int lr = lane & 15, lk = lane >> 4;

  f32x4 acc[4][4] = {};

  for (int k0 = 0; k0 < K; k0 += BKW) {
    {
      const ushort_t* Ap = A + (size_t)m0 * K + k0;
#pragma unroll
      for (int i = 0; i < 4; i++) {
        int rr = rbase + 32 * i;
        short8 v = *(const short8*)(Ap + (size_t)rr * K + c * 8);
        *(short8*)(smem + AOFF + swz(rr, rr * 128 + c * 16)) = v;
      }
    }
    {
      const float* Bp = B + (size_t)n0 * K + k0;
#pragma unroll
      for (int i = 0; i < 4; i++) {
        int rr = rbase + 32 * i;
        const float* p = Bp + (size_t)rr * K + c * 8;
        float4 v0 = *(const float4*)p;
        float4 v1 = *(const float4*)(p + 4);
        short8 o;
        o[0] = (short)f2bf(v0.x); o[1] = (short)f2bf(v0.y);
        o[2] = (short)f2bf(v0.z); o[3] = (short)f2bf(v0.w);
        o[4] = (short)f2bf(v1.x); o[5] = (short)f2bf(v1.y);
        o[6] = (short)f2bf(v1.z); o[7] = (short)f2bf(v1.w);
        *(short8*)(smem + BOFF + swz(rr, rr * 128 + c * 16)) = o;
      }
    }
    __syncthreads();
#pragma unroll
    for (int ks = 0; ks < 2; ks++) {
      short8 af[4], bf[4];
#pragma unroll
      for (int m = 0; m < 4; m++) {
        int rr = wr * 64 + m * 16 + lr;
        af[m] = *(const short8*)(smem + AOFF + swz(rr, rr * 128 + ks * 64 + lk * 16));
      }
#pragma unroll
      for (int n = 0; n < 4; n++) {
        int cc = wc * 64 + n * 16 + lr;
        bf[n] = *(const short8*)(smem + BOFF + swz(cc, cc * 128 + ks * 64 + lk * 16));
      }
#pragma unroll
      for (int m = 0; m < 4; m++) {
#pragma unroll
        for (int n = 0; n < 4; n++) {
          acc[m][n] = __builtin_amdgcn_mfma_f32_16x16x32_bf16(af[m], bf[n], acc[m][n], 0, 0, 0);
        }
      }
    }
    __syncthreads();
  }
#pragma unroll
  for (int m = 0; m < 4; m++) {
    int row = m0 + wr * 64 + m * 16 + lk * 4;
#pragma unroll
    for (int n = 0; n < 4; n++) {
      int col = n0 + wc * 64 + n * 16 + lr;
#pragma unroll
      for (int j = 0; j < 4; j++) {
        size_t idx = (size_t)(row + j) * N + col;
        if (scale) C[idx] += scale[(size_t)(row + j) * 8] * acc[m][n][j];
        else       C[idx] = acc[m][n][j];
      }
    }
  }
}

extern "C" void kernel_launch(void* const* d_in, const int* in_sizes, int n_in,
                              void* d_out, int out_size, void* d_ws, size_t ws_size,
                              hipStream_t stream) {
  const float* x    = (const float*)d_in[0];
  const float* gW   = (const float*)d_in[1];
  const float* Wg_e = (const float*)d_in[2];
  const float* Wu_e = (const float*)d_in[3];
  const float* Wd_e = (const float*)d_in[4];
  const float* Wg_s = (const float*)d_in[5];
  const float* Wu_s = (const float*)d_in[6];
  const float* Wd_s = (const float*)d_in[7];
  float* out = (float*)d_out;

  const int T = 2048, DH = 2048, DE = 1408, DS = 2816, E = 8;

  // ws layout: w[T][8] f32 (64KB) | xb [T,DH] bf16 (8MB) | h [T,DS] bf16 (11.5MB)
  float* w = (float*)d_ws;
  ushort_t* xb = (ushort_t*)((char*)d_ws + 65536);
  ushort_t* h  = (ushort_t*)((char*)d_ws + 65536 + (size_t)T * DH * 2);

  router_kernel<<<T, 64, 0, stream>>>(x, gW, w);
  cvt_kernel<<<(T * DH) / (256 * 4), 256, 0, stream>>>(x, xb, T * DH);

  // shared expert
  gateup_kernel<<<dim3(T / BM, DS / BN), 256, 0, stream>>>(xb, Wg_s, Wu_s, h, DS, DH);
  down_kernel<<<dim3(T / BM, DH / BN), 256, 0, stream>>>(h, Wd_s, out, nullptr, DH, DS);

  // routed experts (dense this round)
  for (int e = 0; e < E; e++) {
    gateup_kernel<<<dim3(T / BM, DE / BN), 256, 0, stream>>>(
        xb, Wg_e + (size_t)e * DE * DH, Wu_e + (size_t)e * DE * DH, h, DE, DH);
    down_kernel<<<dim3(T / BM, DH / BN), 256, 0, stream>>>(
        h, Wd_e + (size_t)e * DH * DE, out, w + e, DH, DE);
  }
}

// Round 2
// 1155.366 us; speedup vs baseline: 1.2318x; 1.2318x over previous
//
#include <hip/hip_runtime.h>

using short8 = __attribute__((ext_vector_type(8))) short;
using f32x4  = __attribute__((ext_vector_type(4))) float;
typedef unsigned short ushort_t;

#define T_TOK 2048
#define DH 2048
#define DE 1408
#define DS 2816

__device__ __forceinline__ unsigned short f2bf(float f) {
  unsigned u = __float_as_uint(f);
  u += 0x7FFF + ((u >> 16) & 1);   // round-to-nearest-even
  return (unsigned short)(u >> 16);
}

__device__ __forceinline__ int swz(int r, int byteoff) {
  return byteoff ^ ((r & 7) << 4);   // G4 XOR swizzle for 128B-stride LDS rows
}

// ---------------- router: softmax -> top2 -> per-expert slot assignment ----------------
__global__ void router_kernel(const float* __restrict__ x, const float* __restrict__ gW,
                              int* __restrict__ counts, int* __restrict__ tok_e,
                              int* __restrict__ tok_slot, float* __restrict__ tok_w) {
  int t = blockIdx.x;
  int lane = threadIdx.x;  // 64 = 1 wave
  float acc[8] = {0.f,0.f,0.f,0.f,0.f,0.f,0.f,0.f};
  const float* xt = x + (size_t)t * DH;
  for (int i = lane; i < DH; i += 64) {
    float xv = xt[i];
#pragma unroll
    for (int e = 0; e < 8; e++) acc[e] += xv * gW[e * DH + i];
  }
#pragma unroll
  for (int e = 0; e < 8; e++) {
#pragma unroll
    for (int off = 32; off > 0; off >>= 1) acc[e] += __shfl_xor(acc[e], off);
  }
  if (lane == 0) {
    float mx = acc[0];
    for (int e = 1; e < 8; e++) mx = fmaxf(mx, acc[e]);
    float p[8], se = 0.f;
    for (int e = 0; e < 8; e++) { p[e] = __expf(acc[e] - mx); se += p[e]; }
    for (int e = 0; e < 8; e++) p[e] /= se;
    int i1 = 0;
    for (int e = 1; e < 8; e++) if (p[e] > p[i1]) i1 = e;
    int i2 = (i1 == 0) ? 1 : 0;
    for (int e = 0; e < 8; e++) if (e != i1 && p[e] > p[i2]) i2 = e;
    int s1 = atomicAdd(&counts[i1], 1);
    int s2 = atomicAdd(&counts[i2], 1);
    tok_e[2 * t] = i1;     tok_e[2 * t + 1] = i2;
    tok_slot[2 * t] = s1;  tok_slot[2 * t + 1] = s2;
    tok_w[2 * t] = p[i1];  tok_w[2 * t + 1] = p[i2];
  }
}

// ---------------- prefix over 8 counts + global-slot assignment ----------------
__global__ void prefix_assign_kernel(const int* __restrict__ counts, int* __restrict__ base,
                                     const int* __restrict__ tok_e, int* __restrict__ tok_slot,
                                     int* __restrict__ slot2tok) {
  __shared__ int sbase[8];
  if (threadIdx.x == 0) {
    int a = 0;
    for (int e = 0; e < 8; e++) { sbase[e] = a; base[e] = a; a += counts[e]; }
  }
  __syncthreads();
  for (int idx = threadIdx.x; idx < T_TOK * 2; idx += blockDim.x) {
    int e = tok_e[idx];
    int g = sbase[e] + tok_slot[idx];
    tok_slot[idx] = g;            // becomes global slot
    slot2tok[g] = idx >> 1;       // token id
  }
}

// ---------------- x f32 -> bf16 ----------------
__global__ void cvt_kernel(const float* __restrict__ x, ushort_t* __restrict__ xb, int n) {
  int i = (blockIdx.x * blockDim.x + threadIdx.x) * 4;
  if (i >= n) return;
  float4 v = *(const float4*)(x + i);
  ushort4 o = { f2bf(v.x), f2bf(v.y), f2bf(v.z), f2bf(v.w) };
  *(ushort4*)(xb + i) = o;
}

// ---------------- batched fused gate+up: z<8 routed (compacted), z=8,9 shared halves ----------------
#define BM 128
#define BN 128
#define BKW 64

__global__ __launch_bounds__(256, 2) void gateup_kernel(
    const ushort_t* __restrict__ xb, const int* __restrict__ counts,
    const int* __restrict__ ebase, const int* __restrict__ slot2tok,
    const float* __restrict__ Wg_e, const float* __restrict__ Wu_e,
    const float* __restrict__ Wg_s, const float* __restrict__ Wu_s,
    ushort_t* __restrict__ h_r, ushort_t* __restrict__ h_s) {
  __shared__ char smem[3 * BM * BKW * 2];
  const int AOFF = 0, GOFF = BM * BKW * 2, UOFF = 2 * BM * BKW * 2;
  int z = blockIdx.z;
  int m0 = blockIdx.x * BM, n0 = blockIdx.y * BN;
  bool routed = (z < 8);
  int cnt, gbase;
  const float *Bg, *Bu;
  if (routed) {
    cnt = counts[z];
    if (m0 >= cnt) return;
    gbase = ebase[z];
    Bg = Wg_e + (size_t)z * DE * DH;
    Bu = Wu_e + (size_t)z * DE * DH;
  } else {
    cnt = T_TOK; gbase = 0;
    int s = z - 8;
    Bg = Wg_s + (size_t)s * 1408 * DH;
    Bu = Wu_s + (size_t)s * 1408 * DH;
  }
  int tid = threadIdx.x;
  int c = tid & 7, rbase = tid >> 3;
  int wid = tid >> 6, lane = tid & 63;
  int wr = wid >> 1, wc = wid & 1;
  int lr = lane & 15, lk = lane >> 4;

  // hoist row pointers (constant across K loop)
  const ushort_t* arow[4];
  const float* bgrow[4];
  const float* burow[4];
#pragma unroll
  for (int i = 0; i < 4; i++) {
    int rr = rbase + 32 * i;
    int lrow = m0 + rr;
    int tok;
    if (routed) tok = (lrow < cnt) ? slot2tok[gbase + lrow] : 0;
    else        tok = lrow;
    arow[i]  = xb + (size_t)tok * DH;
    bgrow[i] = Bg + (size_t)(n0 + rr) * DH;
    burow[i] = Bu + (size_t)(n0 + rr) * DH;
  }

  f32x4 accg[4][4] = {};
  f32x4 accu[4][4] = {};

  for (int k0 = 0; k0 < DH; k0 += BKW) {
#pragma unroll
    for (int i = 0; i < 4; i++) {
      int rr = rbase + 32 * i;
      short8 v = *(const short8*)(arow[i] + k0 + c * 8);
      *(short8*)(smem + AOFF + swz(rr, rr * 128 + c * 16)) = v;
      float4 g0 = *(const float4*)(bgrow[i] + k0 + c * 8);
      float4 g1 = *(const float4*)(bgrow[i] + k0 + c * 8 + 4);
      short8 og;
      og[0] = (short)f2bf(g0.x); og[1] = (short)f2bf(g0.y);
      og[2] = (short)f2bf(g0.z); og[3] = (short)f2bf(g0.w);
      og[4] = (short)f2bf(g1.x); og[5] = (short)f2bf(g1.y);
      og[6] = (short)f2bf(g1.z); og[7] = (short)f2bf(g1.w);
      *(short8*)(smem + GOFF + swz(rr, rr * 128 + c * 16)) = og;
      float4 u0 = *(const float4*)(burow[i] + k0 + c * 8);
      float4 u1 = *(const float4*)(burow[i] + k0 + c * 8 + 4);
      short8 ou;
      ou[0] = (short)f2bf(u0.x); ou[1] = (short)f2bf(u0.y);
      ou[2] = (short)f2bf(u0.z); ou[3] = (short)f2bf(u0.w);
      ou[4] = (short)f2bf(u1.x); ou[5] = (short)f2bf(u1.y);
      ou[6] = (short)f2bf(u1.z); ou[7] = (short)f2bf(u1.w);
      *(short8*)(smem + UOFF + swz(rr, rr * 128 + c * 16)) = ou;
    }
    __syncthreads();
#pragma unroll
    for (int ks = 0; ks < 2; ks++) {
      short8 af[4], bg[4], bu[4];
#pragma unroll
      for (int m = 0; m < 4; m++) {
        int rr = wr * 64 + m * 16 + lr;
        af[m] = *(const short8*)(smem + AOFF + swz(rr, rr * 128 + ks * 64 + lk * 16));
      }
#pragma unroll
      for (int n = 0; n < 4; n++) {
        int cc = wc * 64 + n * 16 + lr;
        bg[n] = *(const short8*)(smem + GOFF + swz(cc, cc * 128 + ks * 64 + lk * 16));
        bu[n] = *(const short8*)(smem + UOFF + swz(cc, cc * 128 + ks * 64 + lk * 16));
      }
#pragma unroll
      for (int m = 0; m < 4; m++) {
#pragma unroll
        for (int n = 0; n < 4; n++) {
          accg[m][n] = __builtin_amdgcn_mfma_f32_16x16x32_bf16(af[m], bg[n], accg[m][n], 0, 0, 0);
          accu[m][n] = __builtin_amdgcn_mfma_f32_16x16x32_bf16(af[m], bu[n], accu[m][n], 0, 0, 0);
        }
      }
    }
    __syncthreads();
  }
  // epilogue: h = bf16(silu(g)*u)
#pragma unroll
  for (int m = 0; m < 4; m++) {
    int rowl = m0 + wr * 64 + m * 16 + lk * 4;
#pragma unroll
    for (int n = 0; n < 4; n++) {
      int col = n0 + wc * 64 + n * 16 + lr;
#pragma unroll
      for (int j = 0; j < 4; j++) {
        float g = accg[m][n][j], u = accu[m][n][j];
        float s = g / (1.f + __expf(-g));
        unsigned short hv = f2bf(s * u);
        if (routed) {
          if (rowl + j < cnt) h_r[(size_t)(gbase + rowl + j) * DE + col] = hv;
        } else {
          h_s[(size_t)(rowl + j) * DS + (z - 8) * 1408 + col] = hv;
        }
      }
    }
  }
}

// ---------------- batched down: z<8 routed -> oe (f32), z=8 shared -> out (store) ----------------
__global__ __launch_bounds__(256, 2) void down_kernel(
    const ushort_t* __restrict__ h_r, const ushort_t* __restrict__ h_s,
    const int* __restrict__ counts, const int* __restrict__ ebase,
    const float* __restrict__ Wd_e, const float* __restrict__ Wd_s,
    float* __restrict__ oe, float* __restrict__ out) {
  __shared__ char smem[2 * BM * BKW * 2];
  const int AOFF = 0, BOFF = BM * BKW * 2;
  int z = blockIdx.z;
  int m0 = blockIdx.x * BM, n0 = blockIdx.y * BN;
  bool routed = (z < 8);
  int cnt, gbase, K, Astride;
  const ushort_t* Abase;
  const float* B;
  if (routed) {
    cnt = counts[z];
    if (m0 >= cnt) return;
    gbase = ebase[z];
    K = DE; Astride = DE;
    Abase = h_r + (size_t)gbase * DE;
    B = Wd_e + (size_t)z * DH * DE;
  } else {
    cnt = T_TOK; gbase = 0;
    K = DS; Astride = DS;
    Abase = h_s;
    B = Wd_s;
  }
  int tid = threadIdx.x;
  int c = tid & 7, rbase = tid >> 3;
  int wid = tid >> 6, lane = tid & 63;
  int wr = wid >> 1, wc = wid & 1;
  int lr = lane & 15, lk = lane >> 4;

  const ushort_t* arow[4];
  const float* brow[4];
#pragma unroll
  for (int i = 0; i < 4; i++) {
    int rr = rbase + 32 * i;
    arow[i] = Abase + (size_t)(m0 + rr) * Astride;
    brow[i] = B + (size_t)(n0 + rr) * K;
  }

  f32x4 acc[4][4] = {};

  for (int k0 = 0; k0 < K; k0 += BKW) {
#pragma unroll
    for (int i = 0; i < 4; i++) {
      int rr = rbase + 32 * i;
      short8 v = *(const short8*)(arow[i] + k0 + c * 8);
      *(short8*)(smem + AOFF + swz(rr, rr * 128 + c * 16)) = v;
      float4 b0 = *(const float4*)(brow[i] + k0 + c * 8);
      float4 b1 = *(const float4*)(brow[i] + k0 + c * 8 + 4);
      short8 ob;
      ob[0] = (short)f2bf(b0.x); ob[1] = (short)f2bf(b0.y);
      ob[2] = (short)f2bf(b0.z); ob[3] = (short)f2bf(b0.w);
      ob[4] = (short)f2bf(b1.x); ob[5] = (short)f2bf(b1.y);
      ob[6] = (short)f2bf(b1.z); ob[7] = (short)f2bf(b1.w);
      *(short8*)(smem + BOFF + swz(rr, rr * 128 + c * 16)) = ob;
    }
    __syncthreads();
#pragma unroll
    for (int ks = 0; ks < 2; ks++) {
      short8 af[4], bf[4];
#pragma unroll
      for (int m = 0; m < 4; m++) {
        int rr = wr * 64 + m * 16 + lr;
        af[m] = *(const short8*)(smem + AOFF + swz(rr, rr * 128 + ks * 64 + lk * 16));
      }
#pragma unroll
      for (int n = 0; n < 4; n++) {
        int cc = wc * 64 + n * 16 + lr;
        bf[n] = *(const short8*)(smem + BOFF + swz(cc, cc * 128 + ks * 64 + lk * 16));
      }
#pragma unroll
      for (int m = 0; m < 4; m++) {
#pragma unroll
        for (int n = 0; n < 4; n++) {
          acc[m][n] = __builtin_amdgcn_mfma_f32_16x16x32_bf16(af[m], bf[n], acc[m][n], 0, 0, 0);
        }
      }
    }
    __syncthreads();
  }
#pragma unroll
  for (int m = 0; m < 4; m++) {
    int rowl = m0 + wr * 64 + m * 16 + lk * 4;
#pragma unroll
    for (int n = 0; n < 4; n++) {
      int col = n0 + wc * 64 + n * 16 + lr;
#pragma unroll
      for (int j = 0; j < 4; j++) {
        if (routed) {
          if (rowl + j < cnt) oe[(size_t)(gbase + rowl + j) * DH + col] = acc[m][n][j];
        } else {
          out[(size_t)(rowl + j) * DH + col] = acc[m][n][j];
        }
      }
    }
  }
}

// ---------------- combine: out[t] += w1*oe[g1] + w2*oe[g2] ----------------
__global__ void combine_kernel(const int* __restrict__ tok_gslot,
                               const float* __restrict__ tok_w,
                               const float* __restrict__ oe,
                               float* __restrict__ out) {
  int t = blockIdx.x;
  int g1 = tok_gslot[2 * t], g2 = tok_gslot[2 * t + 1];
  float w1 = tok_w[2 * t], w2 = tok_w[2 * t + 1];
  int i = threadIdx.x * 8;
  const float4* p1 = (const float4*)(oe + (size_t)g1 * DH + i);
  const float4* p2 = (const float4*)(oe + (size_t)g2 * DH + i);
  float4* po = (float4*)(out + (size_t)t * DH + i);
  float4 a0 = p1[0], a1 = p1[1];
  float4 b0 = p2[0], b1 = p2[1];
  float4 o0 = po[0], o1 = po[1];
  o0.x += w1 * a0.x + w2 * b0.x;  o0.y += w1 * a0.y + w2 * b0.y;
  o0.z += w1 * a0.z + w2 * b0.z;  o0.w += w1 * a0.w + w2 * b0.w;
  o1.x += w1 * a1.x + w2 * b1.x;  o1.y += w1 * a1.y + w2 * b1.y;
  o1.z += w1 * a1.z + w2 * b1.z;  o1.w += w1 * a1.w + w2 * b1.w;
  po[0] = o0; po[1] = o1;
}

extern "C" void kernel_launch(void* const* d_in, const int* in_sizes, int n_in,
                              void* d_out, int out_size, void* d_ws, size_t ws_size,
                              hipStream_t stream) {
  const float* x    = (const float*)d_in[0];
  const float* gW   = (const float*)d_in[1];
  const float* Wg_e = (const float*)d_in[2];
  const float* Wu_e = (const float*)d_in[3];
  const float* Wd_e = (const float*)d_in[4];
  const float* Wg_s = (const float*)d_in[5];
  const float* Wu_s = (const float*)d_in[6];
  const float* Wd_s = (const float*)d_in[7];
  float* out = (float*)d_out;

  char* ws = (char*)d_ws;
  int*   counts   = (int*)ws;                       // 32B (pad to 64)
  int*   ebase    = (int*)(ws + 64);                // 32B
  int*   tok_e    = (int*)(ws + 128);               // 16KB
  int*   tok_slot = (int*)(ws + 128 + 16384);       // 16KB (-> global slots)
  float* tok_w    = (float*)(ws + 128 + 32768);     // 16KB
  int*   slot2tok = (int*)(ws + 128 + 49152);       // 16KB
  ushort_t* xb  = (ushort_t*)(ws + 131072);                              // 8MB
  ushort_t* h_r = (ushort_t*)(ws + 131072 + (size_t)T_TOK * DH * 2);     // 4096*1408*2 = 11.53MB
  ushort_t* h_s = h_r + (size_t)4096 * DE;                               // 2048*2816*2 = 11.53MB
  float*    oe  = (float*)((char*)h_s + (size_t)T_TOK * DS * 2);         // 4096*2048*4 = 32MB

  hipMemsetAsync(counts, 0, 64, stream);
  router_kernel<<<T_TOK, 64, 0, stream>>>(x, gW, counts, tok_e, tok_slot, tok_w);
  prefix_assign_kernel<<<1, 256, 0, stream>>>(counts, ebase, tok_e, tok_slot, slot2tok);
  cvt_kernel<<<(T_TOK * DH) / (256 * 4), 256, 0, stream>>>(x, xb, T_TOK * DH);

  gateup_kernel<<<dim3(16, 11, 10), 256, 0, stream>>>(
      xb, counts, ebase, slot2tok, Wg_e, Wu_e, Wg_s, Wu_s, h_r, h_s);
  down_kernel<<<dim3(16, 16, 9), 256, 0, stream>>>(
      h_r, h_s, counts, ebase, Wd_e, Wd_s, oe, out);
  combine_kernel<<<T_TOK, 256, 0, stream>>>(tok_slot, tok_w, oe, out);
}